// Round 9
// baseline (273.225 us; speedup 1.0000x reference)
//
#include <hip/hip_runtime.h>

#define BB 32
#define CC 64
#define WW 32
#define HHT 32
#define NH 4
#define DHD 16
#define NN 1024   // W*H
#define LOG2E 1.4426950408889634f

typedef __attribute__((ext_vector_type(8))) short bf16x8;
typedef __attribute__((ext_vector_type(4))) float f32x4;

union vfrag_t { bf16x8 s; uint2 d[2]; unsigned u[4]; };

// ---------------- helpers ----------------
__device__ __forceinline__ float wave_sum(float v) {
#pragma unroll
  for (int off = 32; off > 0; off >>= 1) v += __shfl_down(v, off, 64);
  return v;
}
__device__ __forceinline__ float wave_max(float v) {
#pragma unroll
  for (int off = 32; off > 0; off >>= 1) v = fmaxf(v, __shfl_down(v, off, 64));
  return v;
}
__device__ __forceinline__ unsigned bf16pair(float lo, float hi) {
  unsigned a = __float_as_uint(lo), b = __float_as_uint(hi);
  a += 0x7FFFu + ((a >> 16) & 1u);
  b += 0x7FFFu + ((b >> 16) & 1u);
  return (a >> 16) | (b & 0xFFFF0000u);
}
// truncating pack: hi16(f1) | hi16(f0) — one v_perm_b32
__device__ __forceinline__ unsigned bf16pair_trunc(float lo, float hi) {
  return __builtin_amdgcn_perm(__float_as_uint(hi), __float_as_uint(lo), 0x07060302u);
}
__device__ __forceinline__ short bf16s(float f) {
  unsigned a = __float_as_uint(f);
  a += 0x7FFFu + ((a >> 16) & 1u);
  return (short)(a >> 16);
}

// ---------------- MFMA QKV projection (R5 version) ----------------
// KQ: [bh][n][32] bf16, shorts 0..15 = k_d[n]*log2e, 16..31 = q_d[n]
// Vb: [bh][16 d][1024 n] bf16
__global__ __launch_bounds__(256) void qkv_kernel(
    const float* __restrict__ x,
    const float* __restrict__ Wq, const float* __restrict__ bq,
    const float* __restrict__ Wk, const float* __restrict__ bk,
    const float* __restrict__ Wv, const float* __restrict__ bv,
    short* __restrict__ KQ, short* __restrict__ Vb, float* __restrict__ lnzero)
{
  __shared__ __align__(16) short Ws[192 * 72];   // [r][k], r = m*16+dd, stride 72 shorts
  const int tid = threadIdx.x;
  const int b = blockIdx.y, nt = blockIdx.x;

  if (tid < 192) {
    const int m = tid >> 4, dd = tid & 15;
    const int mat = m >> 2, h = m & 3;
    const float* src = (mat == 0 ? Wk : (mat == 1 ? Wq : Wv)) + (h * 16 + dd) * CC;
    const float scale = (mat == 0) ? LOG2E : 1.f;
    short* dst = Ws + tid * 72;
#pragma unroll
    for (int c8 = 0; c8 < 8; ++c8) {
      const float4 f0 = *reinterpret_cast<const float4*>(src + c8 * 8);
      const float4 f1 = *reinterpret_cast<const float4*>(src + c8 * 8 + 4);
      uint4 u;
      u.x = bf16pair(f0.x*scale, f0.y*scale); u.y = bf16pair(f0.z*scale, f0.w*scale);
      u.z = bf16pair(f1.x*scale, f1.y*scale); u.w = bf16pair(f1.z*scale, f1.w*scale);
      *reinterpret_cast<uint4*>(dst + c8 * 8) = u;
    }
  }
  if (blockIdx.x == 0 && blockIdx.y == 0 && tid < 64) lnzero[tid] = 0.f;  // lnsum+lnsum2
  __syncthreads();

  const int wid = tid >> 6, lane = tid & 63, Q = lane >> 4, il = lane & 15;
  const int n = nt * 64 + wid * 16 + il;
  const float* xb = x + (size_t)b * CC * NN;

  union { bf16x8 s; unsigned u[4]; } bfr[2];
#pragma unroll
  for (int half = 0; half < 2; ++half) {
#pragma unroll
    for (int p = 0; p < 4; ++p) {
      const int c0 = 32 * half + 8 * Q + 2 * p;
      const float f0 = xb[(size_t)c0 * NN + n];
      const float f1 = xb[(size_t)(c0 + 1) * NN + n];
      bfr[half].u[p] = bf16pair(f0, f1);
    }
  }

  const f32x4 zero4 = {0.f, 0.f, 0.f, 0.f};
  f32x4 acc[12];
#pragma unroll
  for (int m = 0; m < 12; ++m) {
    const short* wr = Ws + (m * 16 + il) * 72;
    const bf16x8 a0 = *reinterpret_cast<const bf16x8*>(wr + 8 * Q);
    const bf16x8 a1 = *reinterpret_cast<const bf16x8*>(wr + 32 + 8 * Q);
    acc[m] = __builtin_amdgcn_mfma_f32_16x16x32_bf16(a0, bfr[0].s, zero4, 0, 0, 0);
    acc[m] = __builtin_amdgcn_mfma_f32_16x16x32_bf16(a1, bfr[1].s, acc[m], 0, 0, 0);
  }

#pragma unroll
  for (int m = 0; m < 12; ++m) {
    const int mat = m >> 2, h = m & 3;
    const float bsc = (mat == 0) ? LOG2E : 1.f;
    const float4 bias = *reinterpret_cast<const float4*>(
        (mat == 0 ? bk : (mat == 1 ? bq : bv)) + h * 16 + 4 * Q);
    const float v0 = acc[m][0] + bias.x*bsc, v1 = acc[m][1] + bias.y*bsc;
    const float v2 = acc[m][2] + bias.z*bsc, v3 = acc[m][3] + bias.w*bsc;
    if (mat < 2) {
      uint2 pk;
      pk.x = bf16pair(v0, v1); pk.y = bf16pair(v2, v3);
      *reinterpret_cast<uint2*>(KQ + ((size_t)(b * NH + h) * NN + n) * 32 +
                                (mat == 0 ? 0 : 16) + 4 * Q) = pk;
    } else {
      short* vb = Vb + ((size_t)(b * NH + h) * 16 + 4 * Q) * NN + n;
      vb[0]            = bf16s(v0);
      vb[(size_t)NN]   = bf16s(v1);
      vb[2*(size_t)NN] = bf16s(v2);
      vb[3*(size_t)NN] = bf16s(v3);
    }
  }
}

// ---------------- MFMA flash attention v5: j-split, 8 waves/block, LDS combine ----
// Block = 512 threads: waves 0-3 cover j[0,512), waves 4-7 j[512,1024), each 64 i.
// Partial acc/lp combined through LDS; O written coalesced; LN partials fused.
#define OSTRIDE 260
__global__ __launch_bounds__(512, 4) void flash_kernel(
    const short* __restrict__ KQ, const short* __restrict__ Vb,
    const float* __restrict__ rel_h, const float* __restrict__ rel_w,
    float* __restrict__ attnout, float* __restrict__ lnsum, float* __restrict__ lnsum2)
{
  __shared__ __align__(16) float Olds[2*16*OSTRIDE];   // [jh][d][i_local], pad 260
  __shared__ float lpl[2*256];                          // [jh][i_local]
  __shared__ float r1[8], r2[8];
  const int tid = threadIdx.x;
  const int wid = tid >> 6, lane = tid & 63;
  const int Q = lane >> 4, il = lane & 15;
  const int jh = wid >> 2, iquad = wid & 3;
  const int bh = blockIdx.x;
  const int h = bh & 3, b = bh >> 2;
  const int iblk = blockIdx.y * 256;       // block's i range: iblk .. iblk+255
  const int ibase = iblk + iquad * 64;     // this wave's 64 i
  const int jbase = jh * 512;

  // B-frags: a_i = [q(:,i) ; pos(:,i)*log2e], k-slot = 8Q + t, col i = ibase+16g2+il
  bf16x8 bfrag[4];
#pragma unroll
  for (int g2 = 0; g2 < 4; ++g2) {
    const int i = ibase + g2*16 + il;
    if (Q < 2) {
      bfrag[g2] = *reinterpret_cast<const bf16x8*>(KQ + ((size_t)bh*NN + i)*32 + 16 + 8*Q);
    } else {
      const int wrow = i >> 5, hcol = i & 31;
      vfrag_t t;
#pragma unroll
      for (int p = 0; p < 4; ++p) {
        const int d0 = 8*(Q-2) + 2*p;
        const float f0 = LOG2E*(rel_h[(h*DHD + d0)*HHT + hcol] + rel_w[(h*DHD + d0)*WW + wrow]);
        const float f1 = LOG2E*(rel_h[(h*DHD + d0+1)*HHT + hcol] + rel_w[(h*DHD + d0+1)*WW + wrow]);
        t.u[p] = bf16pair(f0, f1);
      }
      bfrag[g2] = t.s;
    }
  }

  const short* KQb = KQ + (size_t)bh*NN*32 + (size_t)jbase*32;
  const short* Vbb = Vb + ((size_t)bh*16 + il)*NN + jbase;   // il = d for PV B-operand
  const f32x4 zero4 = {0.f, 0.f, 0.f, 0.f};
  f32x4 accA[4] = {zero4, zero4, zero4, zero4};
  f32x4 accB[4] = {zero4, zero4, zero4, zero4};
  float lpA[4] = {0.f, 0.f, 0.f, 0.f};
  float lpB[4] = {0.f, 0.f, 0.f, 0.f};

  // prologue: stream A at local j=0, stream B at local j=256
  bf16x8 agA[4], agB[4];
  vfrag_t bvA[2], bvB[2];
#pragma unroll
  for (int g = 0; g < 4; ++g) {
    agA[g] = *reinterpret_cast<const bf16x8*>(KQb + (size_t)(      16*g + il)*32 + 8*Q);
    agB[g] = *reinterpret_cast<const bf16x8*>(KQb + (size_t)(256 + 16*g + il)*32 + 8*Q);
  }
#pragma unroll
  for (int hh = 0; hh < 2; ++hh) {
    const short* vpA = Vbb + 32*hh + 4*Q;
    const short* vpB = Vbb + 256 + 32*hh + 4*Q;
    bvA[hh].d[0] = *reinterpret_cast<const uint2*>(vpA);
    bvA[hh].d[1] = *reinterpret_cast<const uint2*>(vpA + 16);
    bvB[hh].d[0] = *reinterpret_cast<const uint2*>(vpB);
    bvB[hh].d[1] = *reinterpret_cast<const uint2*>(vpB + 16);
  }

  for (int jt = 0; jt < 256; jt += 64) {
    const int jn = (jt + 64) & 255;          // wraps harmlessly on last iter
    bf16x8 agAn[4], agBn[4];
    vfrag_t bvAn[2], bvBn[2];
#pragma unroll
    for (int g = 0; g < 4; ++g) {
      agAn[g] = *reinterpret_cast<const bf16x8*>(KQb + (size_t)(      jn + 16*g + il)*32 + 8*Q);
      agBn[g] = *reinterpret_cast<const bf16x8*>(KQb + (size_t)(256 + jn + 16*g + il)*32 + 8*Q);
    }
#pragma unroll
    for (int hh = 0; hh < 2; ++hh) {
      const short* vpA = Vbb + jn + 32*hh + 4*Q;
      const short* vpB = Vbb + 256 + jn + 32*hh + 4*Q;
      bvAn[hh].d[0] = *reinterpret_cast<const uint2*>(vpA);
      bvAn[hh].d[1] = *reinterpret_cast<const uint2*>(vpA + 16);
      bvBn[hh].d[0] = *reinterpret_cast<const uint2*>(vpB);
      bvBn[hh].d[1] = *reinterpret_cast<const uint2*>(vpB + 16);
    }

#pragma unroll
    for (int g2 = 0; g2 < 4; ++g2) {
      // ---- stream A chain ----
      {
        float p[4][4];
        unsigned pk[4][2];
#pragma unroll
        for (int g = 0; g < 4; ++g) {
          const f32x4 s = __builtin_amdgcn_mfma_f32_16x16x32_bf16(agA[g], bfrag[g2], zero4, 0, 0, 0);
#pragma unroll
          for (int r = 0; r < 4; ++r) p[g][r] = __builtin_amdgcn_exp2f(s[r]);
          lpA[g2] += (p[g][0] + p[g][1]) + (p[g][2] + p[g][3]);
          pk[g][0] = bf16pair_trunc(p[g][0], p[g][1]);
          pk[g][1] = bf16pair_trunc(p[g][2], p[g][3]);
        }
#pragma unroll
        for (int hh = 0; hh < 2; ++hh) {
          vfrag_t ap;
          ap.u[0] = pk[2*hh][0];   ap.u[1] = pk[2*hh][1];
          ap.u[2] = pk[2*hh+1][0]; ap.u[3] = pk[2*hh+1][1];
          accA[g2] = __builtin_amdgcn_mfma_f32_16x16x32_bf16(ap.s, bvA[hh].s, accA[g2], 0, 0, 0);
        }
      }
      // ---- stream B chain (independent) ----
      {
        float p[4][4];
        unsigned pk[4][2];
#pragma unroll
        for (int g = 0; g < 4; ++g) {
          const f32x4 s = __builtin_amdgcn_mfma_f32_16x16x32_bf16(agB[g], bfrag[g2], zero4, 0, 0, 0);
#pragma unroll
          for (int r = 0; r < 4; ++r) p[g][r] = __builtin_amdgcn_exp2f(s[r]);
          lpB[g2] += (p[g][0] + p[g][1]) + (p[g][2] + p[g][3]);
          pk[g][0] = bf16pair_trunc(p[g][0], p[g][1]);
          pk[g][1] = bf16pair_trunc(p[g][2], p[g][3]);
        }
#pragma unroll
        for (int hh = 0; hh < 2; ++hh) {
          vfrag_t ap;
          ap.u[0] = pk[2*hh][0];   ap.u[1] = pk[2*hh][1];
          ap.u[2] = pk[2*hh+1][0]; ap.u[3] = pk[2*hh+1][1];
          accB[g2] = __builtin_amdgcn_mfma_f32_16x16x32_bf16(ap.s, bvB[hh].s, accB[g2], 0, 0, 0);
        }
      }
    }
#pragma unroll
    for (int g = 0; g < 4; ++g) { agA[g] = agAn[g]; agB[g] = agBn[g]; }
#pragma unroll
    for (int hh = 0; hh < 2; ++hh) { bvA[hh] = bvAn[hh]; bvB[hh] = bvBn[hh]; }
  }

  // write partials to LDS
#pragma unroll
  for (int g2 = 0; g2 < 4; ++g2) {
    float l = lpA[g2] + lpB[g2];
    l += __shfl_xor(l, 16, 64);
    l += __shfl_xor(l, 32, 64);
    if (Q == 0) lpl[jh*256 + iquad*64 + g2*16 + il] = l;
    float* od = Olds + (jh*16 + il)*OSTRIDE + iquad*64 + g2*16 + 4*Q;
#pragma unroll
    for (int r = 0; r < 4; ++r) od[r] = accA[g2][r] + accB[g2][r];
  }
  __syncthreads();

  // combine: 512 threads, 2 passes; coalesced float4 stores per d-row
  float s1 = 0.f, s2 = 0.f;
#pragma unroll
  for (int pass = 0; pass < 2; ++pass) {
    const int d = (tid >> 6) + 8*pass;
    const int i0 = (tid & 63)*4;
    const float4 a = *reinterpret_cast<const float4*>(&Olds[(0*16 + d)*OSTRIDE + i0]);
    const float4 c = *reinterpret_cast<const float4*>(&Olds[(1*16 + d)*OSTRIDE + i0]);
    float4 v;
    v.x = (a.x + c.x) * __builtin_amdgcn_rcpf(lpl[i0+0] + lpl[256+i0+0]);
    v.y = (a.y + c.y) * __builtin_amdgcn_rcpf(lpl[i0+1] + lpl[256+i0+1]);
    v.z = (a.z + c.z) * __builtin_amdgcn_rcpf(lpl[i0+2] + lpl[256+i0+2]);
    v.w = (a.w + c.w) * __builtin_amdgcn_rcpf(lpl[i0+3] + lpl[256+i0+3]);
    *reinterpret_cast<float4*>(&attnout[((size_t)b*CC + h*DHD + d)*NN + iblk + i0]) = v;
    s1 += (v.x + v.y) + (v.z + v.w);
    s2 += (v.x*v.x + v.y*v.y) + (v.z*v.z + v.w*v.w);
  }
  s1 = wave_sum(s1); s2 = wave_sum(s2);
  if (lane == 0) { r1[wid] = s1; r2[wid] = s2; }
  __syncthreads();
  if (tid == 0) {
    float a1 = 0.f, a2 = 0.f;
#pragma unroll
    for (int w = 0; w < 8; ++w) { a1 += r1[w]; a2 += r2[w]; }
    atomicAdd(&lnsum[b], a1);
    atomicAdd(&lnsum2[b], a2);
  }
}

// ---------------- CBAM channel stats ----------------
__global__ __launch_bounds__(256) void cbamstats_kernel(
    const float* __restrict__ x, float* __restrict__ avg, float* __restrict__ mx)
{
  const int bc = blockIdx.x, tid = threadIdx.x;
  const float* p = x + (size_t)bc*NN;
  float s = 0.f, m = -3.0e38f;
  for (int u = tid; u < NN; u += 256) { const float v = p[u]; s += v; m = fmaxf(m, v); }
  s = wave_sum(s); m = wave_max(m);
  __shared__ float rs[4], rm[4];
  const int wid = tid >> 6, lane = tid & 63;
  if (lane == 0) { rs[wid] = s; rm[wid] = m; }
  __syncthreads();
  if (tid == 0) {
    avg[bc] = (rs[0]+rs[1]+rs[2]+rs[3]) * (1.f/NN);
    mx[bc]  = fmaxf(fmaxf(rm[0], rm[1]), fmaxf(rm[2], rm[3]));
  }
}

// ---------------- channel-attention MLP (recomputed per block) + spatial feats ----
__global__ __launch_bounds__(256) void mlpfeat_kernel(
    const float* __restrict__ x, const float* __restrict__ avg, const float* __restrict__ mxv,
    const float* __restrict__ w1, const float* __restrict__ b1,
    const float* __restrict__ w2, const float* __restrict__ b2,
    float* __restrict__ chv, float* __restrict__ feat)
{
  const int b = blockIdx.y, qq = blockIdx.x, tid = threadIdx.x;
  __shared__ float sa[CC], sm[CC], sch[CC];
  __shared__ float ps[4][64], pm[4][64];
  if (tid < CC) { sa[tid] = avg[b*CC + tid]; sm[tid] = mxv[b*CC + tid]; }
  __syncthreads();
  if (tid < CC) {
    float s = 2.f * b2[tid];
#pragma unroll
    for (int o = 0; o < 4; ++o) {
      float ha = b1[o], hm = b1[o];
#pragma unroll
      for (int k = 0; k < CC; ++k) { ha += w1[o*CC + k]*sa[k]; hm += w1[o*CC + k]*sm[k]; }
      s += w2[tid*4 + o] * (fmaxf(ha, 0.f) + fmaxf(hm, 0.f));
    }
    const float c = 1.f/(1.f + __expf(-s));
    sch[tid] = c;
    if (qq == 0) chv[b*CC + tid] = c;
  }
  __syncthreads();
  const int nl = tid & 63, cg = tid >> 6;
  const int n = qq*64 + nl;
  float s = 0.f, m = -3.0e38f;
#pragma unroll
  for (int c = cg*16; c < cg*16 + 16; ++c) {
    const float v = sch[c] * x[((size_t)b*CC + c)*NN + n];
    s += v; m = fmaxf(m, v);
  }
  ps[cg][nl] = s; pm[cg][nl] = m;
  __syncthreads();
  if (cg == 0) {
    const float S = ps[0][nl]+ps[1][nl]+ps[2][nl]+ps[3][nl];
    const float M = fmaxf(fmaxf(pm[0][nl], pm[1][nl]), fmaxf(pm[2][nl], pm[3][nl]));
    feat[(size_t)b*2*NN + n]      = S * (1.f/CC);
    feat[(size_t)b*2*NN + NN + n] = M;
  }
}

// ---------------- 7x7 conv + LN + fused final combine (c-split x8) ----------------
__global__ __launch_bounds__(256) void final_kernel(
    const float* __restrict__ x, const float* __restrict__ attn,
    const float* __restrict__ ln_g, const float* __restrict__ ln_b,
    const float* __restrict__ feat, const float* __restrict__ ch,
    const float* __restrict__ lnsum, const float* __restrict__ lnsum2,
    const float* __restrict__ sa_w, const float* __restrict__ sa_b,
    float* __restrict__ out)
{
  const int b = blockIdx.y;
  const int c0 = blockIdx.z * 8;
  const int n = blockIdx.x*256 + threadIdx.x;
  const int w = n >> 5, hh = n & 31;
  __shared__ float sch[CC];
  __shared__ float swt[98];
  if (threadIdx.x < CC) sch[threadIdx.x] = ch[b*CC + threadIdx.x];
  if (threadIdx.x < 98) swt[threadIdx.x] = sa_w[threadIdx.x];
  __syncthreads();

  float s = sa_b[0];
#pragma unroll
  for (int ci = 0; ci < 2; ++ci)
#pragma unroll
    for (int kh = 0; kh < 7; ++kh) {
      const int wy = w + kh - 3;
      if (wy < 0 || wy >= WW) continue;
#pragma unroll
      for (int kw = 0; kw < 7; ++kw) {
        const int hx = hh + kw - 3;
        if (hx < 0 || hx >= HHT) continue;
        s += feat[((size_t)(b*2) + ci)*NN + wy*HHT + hx] * swt[ci*49 + kh*7 + kw];
      }
    }
  const float sg = 1.f/(1.f + __expf(-s));
  const float inv = 1.f/(CC*NN);
  const float m = lnsum[b]*inv;
  const float var = lnsum2[b]*inv - m*m;
  const float r = rsqrtf(var + 1e-5f);
#pragma unroll
  for (int c = c0; c < c0 + 8; ++c) {
    const size_t idx = ((size_t)b*CC + c)*NN + n;
    const float xa = x[idx];
    const float ln = (attn[idx] - m) * r * ln_g[c*NN + n] + ln_b[c*NN + n];
    out[idx] = ln + 2.f*xa + sg * sch[c] * xa;
  }
}

extern "C" void kernel_launch(void* const* d_in, const int* in_sizes, int n_in,
                              void* d_out, int out_size, void* d_ws, size_t ws_size,
                              hipStream_t stream)
{
  const float* x     = (const float*)d_in[0];
  const float* Wq    = (const float*)d_in[1];
  const float* bq    = (const float*)d_in[2];
  const float* Wk    = (const float*)d_in[3];
  const float* bk    = (const float*)d_in[4];
  const float* Wv    = (const float*)d_in[5];
  const float* bv    = (const float*)d_in[6];
  const float* rel_h = (const float*)d_in[7];
  const float* rel_w = (const float*)d_in[8];
  const float* ln_g  = (const float*)d_in[9];
  const float* ln_b  = (const float*)d_in[10];
  const float* cw1   = (const float*)d_in[11];
  const float* cb1   = (const float*)d_in[12];
  const float* cw2   = (const float*)d_in[13];
  const float* cb2   = (const float*)d_in[14];
  const float* saw   = (const float*)d_in[15];
  const float* sab   = (const float*)d_in[16];
  float* out = (float*)d_out;

  short* KQ = (short*)d_ws;                    // 128*1024*32 shorts = 8 MB
  short* Vb = KQ + (size_t)128*1024*32;        // 128*16*1024 shorts = 4 MB
  float* fs = (float*)(Vb + (size_t)128*16*1024);
  float* lnsum  = fs;             // 32 (+32 lnsum2, zeroed in qkv)
  float* lnsum2 = fs + 32;
  float* avg    = fs + 64;        // 2048
  float* mxv    = avg + 2048;     // 2048
  float* chv    = mxv + 2048;     // 2048
  float* feat   = chv + 2048;     // 65536
  float* attn   = out;            // attention output lives in d_out (in-place final)

  qkv_kernel<<<dim3(16, BB), 256, 0, stream>>>(x, Wq, bq, Wk, bk, Wv, bv, KQ, Vb, lnsum);
  flash_kernel<<<dim3(BB*NH, 4), 512, 0, stream>>>(KQ, Vb, rel_h, rel_w, attn, lnsum, lnsum2);
  cbamstats_kernel<<<BB*CC, 256, 0, stream>>>(x, avg, mxv);
  mlpfeat_kernel<<<dim3(16, BB), 256, 0, stream>>>(x, avg, mxv, cw1, cb1, cw2, cb2, chv, feat);
  final_kernel<<<dim3(4, BB, 8), 256, 0, stream>>>(x, attn, ln_g, ln_b, feat, chv, lnsum, lnsum2, saw, sab, out);
}

// Round 10
// 175.579 us; speedup vs baseline: 1.5561x; 1.5561x over previous
//
#include <hip/hip_runtime.h>

#define BB 32
#define CC 64
#define WW 32
#define HHT 32
#define NH 4
#define DHD 16
#define NN 1024   // W*H
#define LOG2E 1.4426950408889634f

typedef __attribute__((ext_vector_type(8))) short bf16x8;
typedef __attribute__((ext_vector_type(4))) float f32x4;

union vfrag_t { bf16x8 s; uint2 d[2]; unsigned u[4]; };

// ---------------- helpers ----------------
__device__ __forceinline__ float wave_sum(float v) {
#pragma unroll
  for (int off = 32; off > 0; off >>= 1) v += __shfl_down(v, off, 64);
  return v;
}
__device__ __forceinline__ float wave_max(float v) {
#pragma unroll
  for (int off = 32; off > 0; off >>= 1) v = fmaxf(v, __shfl_down(v, off, 64));
  return v;
}
__device__ __forceinline__ unsigned bf16pair(float lo, float hi) {
  unsigned a = __float_as_uint(lo), b = __float_as_uint(hi);
  a += 0x7FFFu + ((a >> 16) & 1u);
  b += 0x7FFFu + ((b >> 16) & 1u);
  return (a >> 16) | (b & 0xFFFF0000u);
}
// truncating pack: hi16(f1) | hi16(f0) — one v_perm_b32
__device__ __forceinline__ unsigned bf16pair_trunc(float lo, float hi) {
  return __builtin_amdgcn_perm(__float_as_uint(hi), __float_as_uint(lo), 0x07060302u);
}
__device__ __forceinline__ short bf16s(float f) {
  unsigned a = __float_as_uint(f);
  a += 0x7FFFu + ((a >> 16) & 1u);
  return (short)(a >> 16);
}

// ---------------- MFMA QKV projection (R5 version) ----------------
// KQ: [bh][n][32] bf16, shorts 0..15 = k_d[n]*log2e, 16..31 = q_d[n]
// Vb: [bh][16 d][1024 n] bf16
__global__ __launch_bounds__(256) void qkv_kernel(
    const float* __restrict__ x,
    const float* __restrict__ Wq, const float* __restrict__ bq,
    const float* __restrict__ Wk, const float* __restrict__ bk,
    const float* __restrict__ Wv, const float* __restrict__ bv,
    short* __restrict__ KQ, short* __restrict__ Vb, float* __restrict__ lnzero)
{
  __shared__ __align__(16) short Ws[192 * 72];   // [r][k], r = m*16+dd, stride 72 shorts
  const int tid = threadIdx.x;
  const int b = blockIdx.y, nt = blockIdx.x;

  if (tid < 192) {
    const int m = tid >> 4, dd = tid & 15;
    const int mat = m >> 2, h = m & 3;
    const float* src = (mat == 0 ? Wk : (mat == 1 ? Wq : Wv)) + (h * 16 + dd) * CC;
    const float scale = (mat == 0) ? LOG2E : 1.f;
    short* dst = Ws + tid * 72;
#pragma unroll
    for (int c8 = 0; c8 < 8; ++c8) {
      const float4 f0 = *reinterpret_cast<const float4*>(src + c8 * 8);
      const float4 f1 = *reinterpret_cast<const float4*>(src + c8 * 8 + 4);
      uint4 u;
      u.x = bf16pair(f0.x*scale, f0.y*scale); u.y = bf16pair(f0.z*scale, f0.w*scale);
      u.z = bf16pair(f1.x*scale, f1.y*scale); u.w = bf16pair(f1.z*scale, f1.w*scale);
      *reinterpret_cast<uint4*>(dst + c8 * 8) = u;
    }
  }
  if (blockIdx.x == 0 && blockIdx.y == 0 && tid < 64) lnzero[tid] = 0.f;  // lnsum+lnsum2
  __syncthreads();

  const int wid = tid >> 6, lane = tid & 63, Q = lane >> 4, il = lane & 15;
  const int n = nt * 64 + wid * 16 + il;
  const float* xb = x + (size_t)b * CC * NN;

  union { bf16x8 s; unsigned u[4]; } bfr[2];
#pragma unroll
  for (int half = 0; half < 2; ++half) {
#pragma unroll
    for (int p = 0; p < 4; ++p) {
      const int c0 = 32 * half + 8 * Q + 2 * p;
      const float f0 = xb[(size_t)c0 * NN + n];
      const float f1 = xb[(size_t)(c0 + 1) * NN + n];
      bfr[half].u[p] = bf16pair(f0, f1);
    }
  }

  const f32x4 zero4 = {0.f, 0.f, 0.f, 0.f};
  f32x4 acc[12];
#pragma unroll
  for (int m = 0; m < 12; ++m) {
    const short* wr = Ws + (m * 16 + il) * 72;
    const bf16x8 a0 = *reinterpret_cast<const bf16x8*>(wr + 8 * Q);
    const bf16x8 a1 = *reinterpret_cast<const bf16x8*>(wr + 32 + 8 * Q);
    acc[m] = __builtin_amdgcn_mfma_f32_16x16x32_bf16(a0, bfr[0].s, zero4, 0, 0, 0);
    acc[m] = __builtin_amdgcn_mfma_f32_16x16x32_bf16(a1, bfr[1].s, acc[m], 0, 0, 0);
  }

#pragma unroll
  for (int m = 0; m < 12; ++m) {
    const int mat = m >> 2, h = m & 3;
    const float bsc = (mat == 0) ? LOG2E : 1.f;
    const float4 bias = *reinterpret_cast<const float4*>(
        (mat == 0 ? bk : (mat == 1 ? bq : bv)) + h * 16 + 4 * Q);
    const float v0 = acc[m][0] + bias.x*bsc, v1 = acc[m][1] + bias.y*bsc;
    const float v2 = acc[m][2] + bias.z*bsc, v3 = acc[m][3] + bias.w*bsc;
    if (mat < 2) {
      uint2 pk;
      pk.x = bf16pair(v0, v1); pk.y = bf16pair(v2, v3);
      *reinterpret_cast<uint2*>(KQ + ((size_t)(b * NH + h) * NN + n) * 32 +
                                (mat == 0 ? 0 : 16) + 4 * Q) = pk;
    } else {
      short* vb = Vb + ((size_t)(b * NH + h) * 16 + 4 * Q) * NN + n;
      vb[0]            = bf16s(v0);
      vb[(size_t)NN]   = bf16s(v1);
      vb[2*(size_t)NN] = bf16s(v2);
      vb[3*(size_t)NN] = bf16s(v3);
    }
  }
}

// ---------------- MFMA flash attention v5: j-split, 8 waves/block, LDS combine ----
// Block = 512 threads: waves 0-3 cover j[0,512), waves 4-7 j[512,1024), each 64 i.
// NOTE: __launch_bounds__ 2nd arg behaves as CUDA min-blocks/CU on this toolchain:
// (512,2) -> 16 waves/CU -> VGPR cap 128 (R9's (512,4) capped at 64 -> 650MB spills).
#define OSTRIDE 260
__global__ __launch_bounds__(512, 2) void flash_kernel(
    const short* __restrict__ KQ, const short* __restrict__ Vb,
    const float* __restrict__ rel_h, const float* __restrict__ rel_w,
    float* __restrict__ attnout, float* __restrict__ lnsum, float* __restrict__ lnsum2)
{
  __shared__ __align__(16) float Olds[2*16*OSTRIDE];   // [jh][d][i_local], pad 260
  __shared__ float lpl[2*256];                          // [jh][i_local]
  __shared__ float r1[8], r2[8];
  const int tid = threadIdx.x;
  const int wid = tid >> 6, lane = tid & 63;
  const int Q = lane >> 4, il = lane & 15;
  const int jh = wid >> 2, iquad = wid & 3;
  const int bh = blockIdx.x;
  const int h = bh & 3, b = bh >> 2;
  const int iblk = blockIdx.y * 256;       // block's i range: iblk .. iblk+255
  const int ibase = iblk + iquad * 64;     // this wave's 64 i
  const int jbase = jh * 512;

  // B-frags: a_i = [q(:,i) ; pos(:,i)*log2e], k-slot = 8Q + t, col i = ibase+16g2+il
  bf16x8 bfrag[4];
#pragma unroll
  for (int g2 = 0; g2 < 4; ++g2) {
    const int i = ibase + g2*16 + il;
    if (Q < 2) {
      bfrag[g2] = *reinterpret_cast<const bf16x8*>(KQ + ((size_t)bh*NN + i)*32 + 16 + 8*Q);
    } else {
      const int wrow = i >> 5, hcol = i & 31;
      vfrag_t t;
#pragma unroll
      for (int p = 0; p < 4; ++p) {
        const int d0 = 8*(Q-2) + 2*p;
        const float f0 = LOG2E*(rel_h[(h*DHD + d0)*HHT + hcol] + rel_w[(h*DHD + d0)*WW + wrow]);
        const float f1 = LOG2E*(rel_h[(h*DHD + d0+1)*HHT + hcol] + rel_w[(h*DHD + d0+1)*WW + wrow]);
        t.u[p] = bf16pair(f0, f1);
      }
      bfrag[g2] = t.s;
    }
  }

  const short* KQb = KQ + (size_t)bh*NN*32 + (size_t)jbase*32;
  const short* Vbb = Vb + ((size_t)bh*16 + il)*NN + jbase;   // il = d for PV B-operand
  const f32x4 zero4 = {0.f, 0.f, 0.f, 0.f};
  f32x4 accA[4] = {zero4, zero4, zero4, zero4};
  f32x4 accB[4] = {zero4, zero4, zero4, zero4};
  float lpA[4] = {0.f, 0.f, 0.f, 0.f};
  float lpB[4] = {0.f, 0.f, 0.f, 0.f};

  // prologue: stream A at local j=0, stream B at local j=256
  bf16x8 agA[4], agB[4];
  vfrag_t bvA[2], bvB[2];
#pragma unroll
  for (int g = 0; g < 4; ++g) {
    agA[g] = *reinterpret_cast<const bf16x8*>(KQb + (size_t)(      16*g + il)*32 + 8*Q);
    agB[g] = *reinterpret_cast<const bf16x8*>(KQb + (size_t)(256 + 16*g + il)*32 + 8*Q);
  }
#pragma unroll
  for (int hh = 0; hh < 2; ++hh) {
    const short* vpA = Vbb + 32*hh + 4*Q;
    const short* vpB = Vbb + 256 + 32*hh + 4*Q;
    bvA[hh].d[0] = *reinterpret_cast<const uint2*>(vpA);
    bvA[hh].d[1] = *reinterpret_cast<const uint2*>(vpA + 16);
    bvB[hh].d[0] = *reinterpret_cast<const uint2*>(vpB);
    bvB[hh].d[1] = *reinterpret_cast<const uint2*>(vpB + 16);
  }

  for (int jt = 0; jt < 256; jt += 64) {
    const int jn = (jt + 64) & 255;          // wraps harmlessly on last iter
    bf16x8 agAn[4], agBn[4];
    vfrag_t bvAn[2], bvBn[2];
#pragma unroll
    for (int g = 0; g < 4; ++g) {
      agAn[g] = *reinterpret_cast<const bf16x8*>(KQb + (size_t)(      jn + 16*g + il)*32 + 8*Q);
      agBn[g] = *reinterpret_cast<const bf16x8*>(KQb + (size_t)(256 + jn + 16*g + il)*32 + 8*Q);
    }
#pragma unroll
    for (int hh = 0; hh < 2; ++hh) {
      const short* vpA = Vbb + jn + 32*hh + 4*Q;
      const short* vpB = Vbb + 256 + jn + 32*hh + 4*Q;
      bvAn[hh].d[0] = *reinterpret_cast<const uint2*>(vpA);
      bvAn[hh].d[1] = *reinterpret_cast<const uint2*>(vpA + 16);
      bvBn[hh].d[0] = *reinterpret_cast<const uint2*>(vpB);
      bvBn[hh].d[1] = *reinterpret_cast<const uint2*>(vpB + 16);
    }

#pragma unroll
    for (int g2 = 0; g2 < 4; ++g2) {
      // ---- stream A chain ----
      {
        float p[4][4];
        unsigned pk[4][2];
#pragma unroll
        for (int g = 0; g < 4; ++g) {
          const f32x4 s = __builtin_amdgcn_mfma_f32_16x16x32_bf16(agA[g], bfrag[g2], zero4, 0, 0, 0);
#pragma unroll
          for (int r = 0; r < 4; ++r) p[g][r] = __builtin_amdgcn_exp2f(s[r]);
          lpA[g2] += (p[g][0] + p[g][1]) + (p[g][2] + p[g][3]);
          pk[g][0] = bf16pair_trunc(p[g][0], p[g][1]);
          pk[g][1] = bf16pair_trunc(p[g][2], p[g][3]);
        }
#pragma unroll
        for (int hh = 0; hh < 2; ++hh) {
          vfrag_t ap;
          ap.u[0] = pk[2*hh][0];   ap.u[1] = pk[2*hh][1];
          ap.u[2] = pk[2*hh+1][0]; ap.u[3] = pk[2*hh+1][1];
          accA[g2] = __builtin_amdgcn_mfma_f32_16x16x32_bf16(ap.s, bvA[hh].s, accA[g2], 0, 0, 0);
        }
      }
      // ---- stream B chain (independent) ----
      {
        float p[4][4];
        unsigned pk[4][2];
#pragma unroll
        for (int g = 0; g < 4; ++g) {
          const f32x4 s = __builtin_amdgcn_mfma_f32_16x16x32_bf16(agB[g], bfrag[g2], zero4, 0, 0, 0);
#pragma unroll
          for (int r = 0; r < 4; ++r) p[g][r] = __builtin_amdgcn_exp2f(s[r]);
          lpB[g2] += (p[g][0] + p[g][1]) + (p[g][2] + p[g][3]);
          pk[g][0] = bf16pair_trunc(p[g][0], p[g][1]);
          pk[g][1] = bf16pair_trunc(p[g][2], p[g][3]);
        }
#pragma unroll
        for (int hh = 0; hh < 2; ++hh) {
          vfrag_t ap;
          ap.u[0] = pk[2*hh][0];   ap.u[1] = pk[2*hh][1];
          ap.u[2] = pk[2*hh+1][0]; ap.u[3] = pk[2*hh+1][1];
          accB[g2] = __builtin_amdgcn_mfma_f32_16x16x32_bf16(ap.s, bvB[hh].s, accB[g2], 0, 0, 0);
        }
      }
    }
#pragma unroll
    for (int g = 0; g < 4; ++g) { agA[g] = agAn[g]; agB[g] = agBn[g]; }
#pragma unroll
    for (int hh = 0; hh < 2; ++hh) { bvA[hh] = bvAn[hh]; bvB[hh] = bvBn[hh]; }
  }

  // write partials to LDS
#pragma unroll
  for (int g2 = 0; g2 < 4; ++g2) {
    float l = lpA[g2] + lpB[g2];
    l += __shfl_xor(l, 16, 64);
    l += __shfl_xor(l, 32, 64);
    if (Q == 0) lpl[jh*256 + iquad*64 + g2*16 + il] = l;
    float* od = Olds + (jh*16 + il)*OSTRIDE + iquad*64 + g2*16 + 4*Q;
#pragma unroll
    for (int r = 0; r < 4; ++r) od[r] = accA[g2][r] + accB[g2][r];
  }
  __syncthreads();

  // combine: 512 threads, 2 passes; coalesced float4 stores per d-row
  float s1 = 0.f, s2 = 0.f;
#pragma unroll
  for (int pass = 0; pass < 2; ++pass) {
    const int d = (tid >> 6) + 8*pass;
    const int i0 = (tid & 63)*4;
    const float4 a = *reinterpret_cast<const float4*>(&Olds[(0*16 + d)*OSTRIDE + i0]);
    const float4 c = *reinterpret_cast<const float4*>(&Olds[(1*16 + d)*OSTRIDE + i0]);
    float4 v;
    v.x = (a.x + c.x) * __builtin_amdgcn_rcpf(lpl[i0+0] + lpl[256+i0+0]);
    v.y = (a.y + c.y) * __builtin_amdgcn_rcpf(lpl[i0+1] + lpl[256+i0+1]);
    v.z = (a.z + c.z) * __builtin_amdgcn_rcpf(lpl[i0+2] + lpl[256+i0+2]);
    v.w = (a.w + c.w) * __builtin_amdgcn_rcpf(lpl[i0+3] + lpl[256+i0+3]);
    *reinterpret_cast<float4*>(&attnout[((size_t)b*CC + h*DHD + d)*NN + iblk + i0]) = v;
    s1 += (v.x + v.y) + (v.z + v.w);
    s2 += (v.x*v.x + v.y*v.y) + (v.z*v.z + v.w*v.w);
  }
  s1 = wave_sum(s1); s2 = wave_sum(s2);
  if (lane == 0) { r1[wid] = s1; r2[wid] = s2; }
  __syncthreads();
  if (tid == 0) {
    float a1 = 0.f, a2 = 0.f;
#pragma unroll
    for (int w = 0; w < 8; ++w) { a1 += r1[w]; a2 += r2[w]; }
    atomicAdd(&lnsum[b], a1);
    atomicAdd(&lnsum2[b], a2);
  }
}

// ---------------- CBAM channel stats ----------------
__global__ __launch_bounds__(256) void cbamstats_kernel(
    const float* __restrict__ x, float* __restrict__ avg, float* __restrict__ mx)
{
  const int bc = blockIdx.x, tid = threadIdx.x;
  const float* p = x + (size_t)bc*NN;
  float s = 0.f, m = -3.0e38f;
  for (int u = tid; u < NN; u += 256) { const float v = p[u]; s += v; m = fmaxf(m, v); }
  s = wave_sum(s); m = wave_max(m);
  __shared__ float rs[4], rm[4];
  const int wid = tid >> 6, lane = tid & 63;
  if (lane == 0) { rs[wid] = s; rm[wid] = m; }
  __syncthreads();
  if (tid == 0) {
    avg[bc] = (rs[0]+rs[1]+rs[2]+rs[3]) * (1.f/NN);
    mx[bc]  = fmaxf(fmaxf(rm[0], rm[1]), fmaxf(rm[2], rm[3]));
  }
}

// ---------------- channel-attention MLP (recomputed per block) + spatial feats ----
__global__ __launch_bounds__(256) void mlpfeat_kernel(
    const float* __restrict__ x, const float* __restrict__ avg, const float* __restrict__ mxv,
    const float* __restrict__ w1, const float* __restrict__ b1,
    const float* __restrict__ w2, const float* __restrict__ b2,
    float* __restrict__ chv, float* __restrict__ feat)
{
  const int b = blockIdx.y, qq = blockIdx.x, tid = threadIdx.x;
  __shared__ float sa[CC], sm[CC], sch[CC];
  __shared__ float ps[4][64], pm[4][64];
  if (tid < CC) { sa[tid] = avg[b*CC + tid]; sm[tid] = mxv[b*CC + tid]; }
  __syncthreads();
  if (tid < CC) {
    float s = 2.f * b2[tid];
#pragma unroll
    for (int o = 0; o < 4; ++o) {
      float ha = b1[o], hm = b1[o];
#pragma unroll
      for (int k = 0; k < CC; ++k) { ha += w1[o*CC + k]*sa[k]; hm += w1[o*CC + k]*sm[k]; }
      s += w2[tid*4 + o] * (fmaxf(ha, 0.f) + fmaxf(hm, 0.f));
    }
    const float c = 1.f/(1.f + __expf(-s));
    sch[tid] = c;
    if (qq == 0) chv[b*CC + tid] = c;
  }
  __syncthreads();
  const int nl = tid & 63, cg = tid >> 6;
  const int n = qq*64 + nl;
  float s = 0.f, m = -3.0e38f;
#pragma unroll
  for (int c = cg*16; c < cg*16 + 16; ++c) {
    const float v = sch[c] * x[((size_t)b*CC + c)*NN + n];
    s += v; m = fmaxf(m, v);
  }
  ps[cg][nl] = s; pm[cg][nl] = m;
  __syncthreads();
  if (cg == 0) {
    const float S = ps[0][nl]+ps[1][nl]+ps[2][nl]+ps[3][nl];
    const float M = fmaxf(fmaxf(pm[0][nl], pm[1][nl]), fmaxf(pm[2][nl], pm[3][nl]));
    feat[(size_t)b*2*NN + n]      = S * (1.f/CC);
    feat[(size_t)b*2*NN + NN + n] = M;
  }
}

// ---------------- 7x7 conv + LN + fused final combine (c-split x8) ----------------
__global__ __launch_bounds__(256) void final_kernel(
    const float* __restrict__ x, const float* __restrict__ attn,
    const float* __restrict__ ln_g, const float* __restrict__ ln_b,
    const float* __restrict__ feat, const float* __restrict__ ch,
    const float* __restrict__ lnsum, const float* __restrict__ lnsum2,
    const float* __restrict__ sa_w, const float* __restrict__ sa_b,
    float* __restrict__ out)
{
  const int b = blockIdx.y;
  const int c0 = blockIdx.z * 8;
  const int n = blockIdx.x*256 + threadIdx.x;
  const int w = n >> 5, hh = n & 31;
  __shared__ float sch[CC];
  __shared__ float swt[98];
  if (threadIdx.x < CC) sch[threadIdx.x] = ch[b*CC + threadIdx.x];
  if (threadIdx.x < 98) swt[threadIdx.x] = sa_w[threadIdx.x];
  __syncthreads();

  float s = sa_b[0];
#pragma unroll
  for (int ci = 0; ci < 2; ++ci)
#pragma unroll
    for (int kh = 0; kh < 7; ++kh) {
      const int wy = w + kh - 3;
      if (wy < 0 || wy >= WW) continue;
#pragma unroll
      for (int kw = 0; kw < 7; ++kw) {
        const int hx = hh + kw - 3;
        if (hx < 0 || hx >= HHT) continue;
        s += feat[((size_t)(b*2) + ci)*NN + wy*HHT + hx] * swt[ci*49 + kh*7 + kw];
      }
    }
  const float sg = 1.f/(1.f + __expf(-s));
  const float inv = 1.f/(CC*NN);
  const float m = lnsum[b]*inv;
  const float var = lnsum2[b]*inv - m*m;
  const float r = rsqrtf(var + 1e-5f);
#pragma unroll
  for (int c = c0; c < c0 + 8; ++c) {
    const size_t idx = ((size_t)b*CC + c)*NN + n;
    const float xa = x[idx];
    const float ln = (attn[idx] - m) * r * ln_g[c*NN + n] + ln_b[c*NN + n];
    out[idx] = ln + 2.f*xa + sg * sch[c] * xa;
  }
}

extern "C" void kernel_launch(void* const* d_in, const int* in_sizes, int n_in,
                              void* d_out, int out_size, void* d_ws, size_t ws_size,
                              hipStream_t stream)
{
  const float* x     = (const float*)d_in[0];
  const float* Wq    = (const float*)d_in[1];
  const float* bq    = (const float*)d_in[2];
  const float* Wk    = (const float*)d_in[3];
  const float* bk    = (const float*)d_in[4];
  const float* Wv    = (const float*)d_in[5];
  const float* bv    = (const float*)d_in[6];
  const float* rel_h = (const float*)d_in[7];
  const float* rel_w = (const float*)d_in[8];
  const float* ln_g  = (const float*)d_in[9];
  const float* ln_b  = (const float*)d_in[10];
  const float* cw1   = (const float*)d_in[11];
  const float* cb1   = (const float*)d_in[12];
  const float* cw2   = (const float*)d_in[13];
  const float* cb2   = (const float*)d_in[14];
  const float* saw   = (const float*)d_in[15];
  const float* sab   = (const float*)d_in[16];
  float* out = (float*)d_out;

  short* KQ = (short*)d_ws;                    // 128*1024*32 shorts = 8 MB
  short* Vb = KQ + (size_t)128*1024*32;        // 128*16*1024 shorts = 4 MB
  float* fs = (float*)(Vb + (size_t)128*16*1024);
  float* lnsum  = fs;             // 32 (+32 lnsum2, zeroed in qkv)
  float* lnsum2 = fs + 32;
  float* avg    = fs + 64;        // 2048
  float* mxv    = avg + 2048;     // 2048
  float* chv    = mxv + 2048;     // 2048
  float* feat   = chv + 2048;     // 65536
  float* attn   = out;            // attention output lives in d_out (in-place final)

  qkv_kernel<<<dim3(16, BB), 256, 0, stream>>>(x, Wq, bq, Wk, bk, Wv, bv, KQ, Vb, lnsum);
  flash_kernel<<<dim3(BB*NH, 4), 512, 0, stream>>>(KQ, Vb, rel_h, rel_w, attn, lnsum, lnsum2);
  cbamstats_kernel<<<BB*CC, 256, 0, stream>>>(x, avg, mxv);
  mlpfeat_kernel<<<dim3(16, BB), 256, 0, stream>>>(x, avg, mxv, cw1, cb1, cw2, cb2, chv, feat);
  final_kernel<<<dim3(4, BB, 8), 256, 0, stream>>>(x, attn, ln_g, ln_b, feat, chv, lnsum, lnsum2, saw, sab, out);
}